// Round 4
// baseline (157.360 us; speedup 1.0000x reference)
//
#include <hip/hip_runtime.h>
#include <hip/hip_bf16.h>
#include <cstdint>
#include <cstddef>

using bf16 = __hip_bfloat16;
typedef __attribute__((ext_vector_type(8))) short short8v;
typedef __attribute__((ext_vector_type(4))) float f32x4;

static constexpr int BATCH = 32;
static constexpr int CH    = 512;   // C
static constexpr int CIc   = 256;   // inter channels
static constexpr int NSP   = 1024;  // H*W
#define EPSV 1e-5f

__device__ __forceinline__ bf16 f2bf(float f) { return __float2bfloat16(f); }

// async global->LDS, 16B per lane; LDS dest = wave-uniform base + lane*16
__device__ __forceinline__ void gload_lds16(const bf16* g, bf16* l) {
  __builtin_amdgcn_global_load_lds(
      (const __attribute__((address_space(1))) void*)g,
      (__attribute__((address_space(3))) void*)l, 16, 0, 0);
}

// ---------------- weight conversion: wcat = [w_g; w_phi; w_theta] bf16, wWb, biascat ----
__global__ __launch_bounds__(256) void convert_weights(
    const float* __restrict__ wg, const float* __restrict__ wph, const float* __restrict__ wth,
    const float* __restrict__ bg, const float* __restrict__ bph, const float* __restrict__ bth,
    const float* __restrict__ wW,
    bf16* __restrict__ wcat, bf16* __restrict__ wWb, float* __restrict__ biascat)
{
  int i = blockIdx.x * 256 + threadIdx.x;
  const int WSZ = CIc * CH; // 131072
  if (i < WSZ) {
    wcat[i]         = f2bf(wg[i]);
    wcat[WSZ + i]   = f2bf(wph[i]);
    wcat[2*WSZ + i] = f2bf(wth[i]);
    wWb[i]          = f2bf(wW[i]);   // w_W is [512][256] = same element count
  }
  if (i < CIc) {
    biascat[i]        = bg[i];
    biascat[CIc + i]  = bph[i];
    biascat[2*CIc + i]= bth[i];
  }
}

// ---------------- x [B,C,N] fp32 -> xt [B,N,C] bf16 ----------------
__global__ __launch_bounds__(256) void transpose_x_kernel(
    const float* __restrict__ x, bf16* __restrict__ xt)
{
  __shared__ bf16 t[32][34];
  int n0 = blockIdx.x * 32, c0 = blockIdx.y * 32, b = blockIdx.z;
  const float* s = x + (size_t)b * CH * NSP;
  bf16* d = xt + (size_t)b * NSP * CH;
  int tx = threadIdx.x & 31, ty = threadIdx.x >> 5; // ty 0..7
  #pragma unroll
  for (int i = 0; i < 32; i += 8)
    t[ty + i][tx] = f2bf(s[(size_t)(c0 + ty + i) * NSP + n0 + tx]);
  __syncthreads();
  #pragma unroll
  for (int i = 0; i < 32; i += 8)
    d[(size_t)(n0 + ty + i) * CH + c0 + tx] = t[tx][ty + i];
}

// ---------------- NT GEMM: C[M][N] = sum_k A[m][k] * B[n][k]  (both bf16 K-major) -------
// FRAGMENT-MAJOR LDS: As/Bs hold 16 fragments of 1KB each per buffer. Fragment
// f = wr*8 + mf*2 + kk (A) / wc*8 + nf*2 + kk (B); within a fragment, slot = lane
// (16B per lane) -> ds_read_b128 at frag_base + lane*16: lane-linear, conflict-free.
// global_load_lds writes linearly, so the PER-LANE GLOBAL SOURCE is permuted to the
// fragment mapping (LDS-linear + pre-permuted source, the verified m173/HK pattern).
// 2-phase double-buffered: stage(t+1) issued before compute(t); one barrier per step.
// EPI 0: store bf16 C
// EPI 1: +bias[row]; rows <512 -> bf16 C (proj: g,phi); rows >=512 -> transposed bf16 to Tt
// EPI 2: final: fp32 out = acc * (a_c/N) + ((bW-mu)*a_c + beta) + x
template<int EPI>
__global__ __launch_bounds__(256) void gemm_nt(
    const bf16* __restrict__ A, size_t sA,
    const bf16* __restrict__ Bm, size_t sB,
    void* __restrict__ Cm, size_t sC,
    int M, int N, int K,
    const float* __restrict__ bias,
    bf16* __restrict__ Tt, size_t sT,
    const float* __restrict__ bW, const float* __restrict__ gma,
    const float* __restrict__ bta, const float* __restrict__ mu,
    const float* __restrict__ var,
    const float* __restrict__ xres, size_t sX)
{
  __shared__ bf16 As[2][128 * 64];   // 16 frags x 512 elems (1KB) per buffer
  __shared__ bf16 Bs[2][128 * 64];
  const int b  = blockIdx.z;
  const int m0 = blockIdx.y * 128;
  const int n0 = blockIdx.x * 128;
  const bf16* Ab = A  + (size_t)b * sA;
  const bf16* Bb = Bm + (size_t)b * sB;
  const int tid  = threadIdx.x;
  const int wv   = tid >> 6, lane = tid & 63;
  const int l16  = lane & 15, g4 = lane >> 4;
  const int wr   = wv >> 1,  wc = wv & 1;

  f32x4 acc[4][4];
  #pragma unroll
  for (int i = 0; i < 4; ++i)
    #pragma unroll
    for (int j = 0; j < 4; ++j)
      acc[i][j] = (f32x4){0.f, 0.f, 0.f, 0.f};

  // Stage tile (ks) into buffer p, fragment-major. Wave wv stages fragments
  // {i*4+wv}. LDS dest is wave-uniform base (frag*512 elems); HW adds lane*16B.
  // Global source per lane: frag -> (blk, sub, kk); row = blk*64+sub*16+l16,
  // k = ks + kk*32 + g4*8. Lanes {l, l+16, l+32, l+48} share a row -> 64B-merged.
  auto stage = [&](int ks, int p) {
    #pragma unroll
    for (int i = 0; i < 4; ++i) {
      int frag = i * 4 + wv;
      int blk = frag >> 3, sub = (frag >> 1) & 3, kk = frag & 1;
      int row = blk * 64 + sub * 16 + l16;
      int kel = ks + kk * 32 + g4 * 8;
      gload_lds16(Ab + (size_t)(m0 + row) * K + kel, &As[p][frag * 512]);
      gload_lds16(Bb + (size_t)(n0 + row) * K + kel, &Bs[p][frag * 512]);
    }
  };

  const int nt = K >> 6;
  stage(0, 0);
  __syncthreads();                       // prologue: full drain for tile 0 only
  for (int t = 0; t < nt; ++t) {
    const int cur = t & 1;
    if (t + 1 < nt) stage((t + 1) << 6, cur ^ 1);   // in flight during MFMAs
    #pragma unroll
    for (int kk = 0; kk < 2; ++kk) {
      short8v af[4], bfv[4];
      #pragma unroll
      for (int mf = 0; mf < 4; ++mf)
        af[mf] = *(const short8v*)&As[cur][(wr * 8 + mf * 2 + kk) * 512 + lane * 8];
      #pragma unroll
      for (int nf = 0; nf < 4; ++nf)
        bfv[nf] = *(const short8v*)&Bs[cur][(wc * 8 + nf * 2 + kk) * 512 + lane * 8];
      #pragma unroll
      for (int mf = 0; mf < 4; ++mf)
        #pragma unroll
        for (int nf = 0; nf < 4; ++nf)
          acc[mf][nf] = __builtin_amdgcn_mfma_f32_16x16x32_bf16(af[mf], bfv[nf], acc[mf][nf], 0, 0, 0);
    }
    __syncthreads();   // drains t+1 loads (post-compute) + syncs readers of buf[cur]
  }

  const int colbase = n0 + wc * 64 + l16;
  const int rowbase = m0 + wr * 64 + g4 * 4;

  if constexpr (EPI == 2) {
    #pragma unroll
    for (int mf = 0; mf < 4; ++mf) {
      #pragma unroll
      for (int j = 0; j < 4; ++j) {
        int row = rowbase + mf * 16 + j;
        float a  = gma[row] * rsqrtf(var[row] + EPSV);
        float bb = (bW[row] - mu[row]) * a + bta[row];
        float sc = a * (1.f / (float)NSP);
        #pragma unroll
        for (int nf = 0; nf < 4; ++nf) {
          int col = colbase + nf * 16;
          ((float*)Cm)[(size_t)b * sC + (size_t)row * N + col] =
              acc[mf][nf][j] * sc + bb + xres[(size_t)b * sX + (size_t)row * N + col];
        }
      }
    }
  } else if constexpr (EPI == 1) {
    if (m0 >= 512) {
      // theta rows: store transposed -> Tt[b][col][row-512], bias included, 8B packed
      #pragma unroll
      for (int mf = 0; mf < 4; ++mf) {
        int rowt0 = (m0 - 512) + wr * 64 + mf * 16 + g4 * 4;
        #pragma unroll
        for (int nf = 0; nf < 4; ++nf) {
          int col = colbase + nf * 16;
          uint64_t pk = 0;
          #pragma unroll
          for (int j = 0; j < 4; ++j) {
            bf16 bv = f2bf(acc[mf][nf][j] + bias[512 + rowt0 + j]);
            pk |= (uint64_t)(*(unsigned short*)&bv) << (16 * j);
          }
          *(uint64_t*)(Tt + (size_t)b * sT + (size_t)col * CIc + rowt0) = pk;
        }
      }
    } else {
      #pragma unroll
      for (int mf = 0; mf < 4; ++mf)
        #pragma unroll
        for (int j = 0; j < 4; ++j) {
          int row = rowbase + mf * 16 + j;
          float badd = bias[row];
          #pragma unroll
          for (int nf = 0; nf < 4; ++nf) {
            int col = colbase + nf * 16;
            ((bf16*)Cm)[(size_t)b * sC + (size_t)row * N + col] = f2bf(acc[mf][nf][j] + badd);
          }
        }
    }
  } else {
    #pragma unroll
    for (int mf = 0; mf < 4; ++mf)
      #pragma unroll
      for (int j = 0; j < 4; ++j) {
        int row = rowbase + mf * 16 + j;
        #pragma unroll
        for (int nf = 0; nf < 4; ++nf) {
          int col = colbase + nf * 16;
          ((bf16*)Cm)[(size_t)b * sC + (size_t)row * N + col] = f2bf(acc[mf][nf][j]);
        }
      }
  }
}

extern "C" void kernel_launch(void* const* d_in, const int* in_sizes, int n_in,
                              void* d_out, int out_size, void* d_ws, size_t ws_size,
                              hipStream_t stream)
{
  const float* x    = (const float*)d_in[0];
  const float* w_g  = (const float*)d_in[1];
  const float* b_g  = (const float*)d_in[2];
  const float* w_th = (const float*)d_in[3];
  const float* b_th = (const float*)d_in[4];
  const float* w_ph = (const float*)d_in[5];
  const float* b_ph = (const float*)d_in[6];
  const float* w_W  = (const float*)d_in[7];
  const float* b_W  = (const float*)d_in[8];
  const float* gma  = (const float*)d_in[9];
  const float* bta  = (const float*)d_in[10];
  const float* mu   = (const float*)d_in[11];
  const float* var  = (const float*)d_in[12];
  float* out = (float*)d_out;

  // workspace layout (bytes), total ~93 MB
  char* ws = (char*)d_ws;
  bf16* proj = (bf16*)(ws + 0);            // [32][512][1024]  rows: g(0-255), phi(256-511)
  bf16* xt   = (bf16*)(ws + 33554432);     // [32][1024][512]  x^T bf16
  bf16* thT  = (bf16*)(ws + 67108864);     // [32][1024][256]  theta^T
  bf16* S    = (bf16*)(ws + 83886080);     // [32][256][256]   S = phi g^T
  bf16* T    = (bf16*)(ws + 88080384);     // [32][512][256]   T = wW S^T
  bf16* wcat = (bf16*)(ws + 96468992);     // [768][512]
  bf16* wWb  = (bf16*)(ws + 97255424);     // [512][256]
  float* bcat= (float*)(ws + 97517568);    // [768]

  convert_weights<<<512, 256, 0, stream>>>(w_g, w_ph, w_th, b_g, b_ph, b_th, w_W, wcat, wWb, bcat);
  transpose_x_kernel<<<dim3(32, 16, 32), 256, 0, stream>>>(x, xt);

  // K1: proj/thT = Wcat . xt^T + bias   (M=768, N=1024, K=512)
  gemm_nt<1><<<dim3(8, 6, 32), 256, 0, stream>>>(
      wcat, 0, xt, (size_t)NSP * CH, proj, (size_t)CH * NSP,
      768, NSP, CH, bcat, thT, (size_t)NSP * CIc,
      nullptr, nullptr, nullptr, nullptr, nullptr, nullptr, 0);

  // K2: S = phi . g^T   (M=256, N=256, K=1024)
  gemm_nt<0><<<dim3(2, 2, 32), 256, 0, stream>>>(
      proj + 256 * 1024, (size_t)CH * NSP, proj, (size_t)CH * NSP, S, (size_t)CIc * CIc,
      CIc, CIc, NSP, nullptr, nullptr, 0,
      nullptr, nullptr, nullptr, nullptr, nullptr, nullptr, 0);

  // K3: T = wW . S^T    (M=512, N=256, K=256)
  gemm_nt<0><<<dim3(2, 4, 32), 256, 0, stream>>>(
      wWb, 0, S, (size_t)CIc * CIc, T, (size_t)CH * CIc,
      CH, CIc, CIc, nullptr, nullptr, 0,
      nullptr, nullptr, nullptr, nullptr, nullptr, nullptr, 0);

  // K4: out = BN(T . thT^T / N + bW) + x   (M=512, N=1024, K=256)
  gemm_nt<2><<<dim3(8, 4, 32), 256, 0, stream>>>(
      T, (size_t)CH * CIc, thT, (size_t)NSP * CIc, out, (size_t)CH * NSP,
      CH, NSP, CIc, nullptr, nullptr, 0,
      b_W, gma, bta, mu, var, x, (size_t)CH * NSP);
}

// Round 5
// 135.420 us; speedup vs baseline: 1.1620x; 1.1620x over previous
//
#include <hip/hip_runtime.h>
#include <hip/hip_bf16.h>
#include <cstdint>
#include <cstddef>

using bf16 = __hip_bfloat16;
typedef __attribute__((ext_vector_type(8))) short short8v;
typedef __attribute__((ext_vector_type(4))) float f32x4;

static constexpr int BATCH = 32;
static constexpr int CH    = 512;   // C
static constexpr int CIc   = 256;   // inter channels
static constexpr int NSP   = 1024;  // H*W
#define EPSV 1e-5f

__device__ __forceinline__ bf16 f2bf(float f) { return __float2bfloat16(f); }

// async global->LDS, 16B per lane; LDS dest = wave-uniform base + lane*16
__device__ __forceinline__ void gload_lds16(const bf16* g, bf16* l) {
  __builtin_amdgcn_global_load_lds(
      (const __attribute__((address_space(1))) void*)g,
      (__attribute__((address_space(3))) void*)l, 16, 0, 0);
}

// ---------------- weight conversion ----------------
__global__ __launch_bounds__(256) void convert_weights(
    const float* __restrict__ wg, const float* __restrict__ wph, const float* __restrict__ wth,
    const float* __restrict__ bg, const float* __restrict__ bph, const float* __restrict__ bth,
    const float* __restrict__ wW,
    bf16* __restrict__ wcat, bf16* __restrict__ wWb, float* __restrict__ biascat)
{
  int i = blockIdx.x * 256 + threadIdx.x;
  const int WSZ = CIc * CH; // 131072
  if (i < WSZ) {
    wcat[i]         = f2bf(wg[i]);
    wcat[WSZ + i]   = f2bf(wph[i]);
    wcat[2*WSZ + i] = f2bf(wth[i]);
    wWb[i]          = f2bf(wW[i]);
  }
  if (i < CIc) {
    biascat[i]        = bg[i];
    biascat[CIc + i]  = bph[i];
    biascat[2*CIc + i]= bth[i];
  }
}

// ---------------- x [B,C,N] fp32 -> xt [B,N,C] bf16 ----------------
__global__ __launch_bounds__(256) void transpose_x_kernel(
    const float* __restrict__ x, bf16* __restrict__ xt)
{
  __shared__ bf16 t[32][34];
  int n0 = blockIdx.x * 32, c0 = blockIdx.y * 32, b = blockIdx.z;
  const float* s = x + (size_t)b * CH * NSP;
  bf16* d = xt + (size_t)b * NSP * CH;
  int tx = threadIdx.x & 31, ty = threadIdx.x >> 5;
  #pragma unroll
  for (int i = 0; i < 32; i += 8)
    t[ty + i][tx] = f2bf(s[(size_t)(c0 + ty + i) * NSP + n0 + tx]);
  __syncthreads();
  #pragma unroll
  for (int i = 0; i < 32; i += 8)
    d[(size_t)(n0 + ty + i) * CH + c0 + tx] = t[tx][ty + i];
}

// ============ 256x256 deep-pipelined NT GEMM (derived-waits, T3+T4+T2+T5) ============
// 512 thr = 8 waves (wr=wv>>2 in {0,1}: 128 rows; wc=wv&3: 64 cols). BK=64, 2 K-halves.
// LDS: 2 dbuf x 2 half x [256][32] for A and B = 128KB. Swizzle: cell (row, slot s)
// holds global k-slot s ^ ((row>>1)&3)  (involution applied on stage SOURCE and read).
// Pipeline: half-stages (4 gloads) issued ~1.5 tiles ahead; raw s_barrier; counted
// vmcnt(8) per phase keeps 8-12 loads in flight across barriers (never vmcnt(0) in loop).
// EPI 1 (K1): rows<512 -> proj bf16 +bias (b = col>>10); m-tile 2 -> thT transposed.
// EPI 2 (K4): fp32 out = acc*(a/N) + ((bW-mu)*a+beta) + x, batch = blockIdx.z.
template<int EPI>
__global__ __launch_bounds__(512, 1) void gemm_nt_256(
    const bf16* __restrict__ A, size_t sA,
    const bf16* __restrict__ Bm, size_t sB,
    void* __restrict__ Cm,
    int K,
    const float* __restrict__ bias,
    bf16* __restrict__ Tt,
    const float* __restrict__ bW, const float* __restrict__ gma,
    const float* __restrict__ bta, const float* __restrict__ mu,
    const float* __restrict__ var,
    const float* __restrict__ xres)
{
  __shared__ bf16 As[2][2][256][32];   // [dbuf][half][row][kel]  64KB
  __shared__ bf16 Bs[2][2][256][32];   // 64KB
  const int zb = blockIdx.z;
  const int m0 = blockIdx.y * 256;
  const int n0 = blockIdx.x * 256;
  const bf16* Ab = A  + (size_t)zb * sA;
  const bf16* Bb = Bm + (size_t)zb * sB;
  const int tid  = threadIdx.x;
  const int wv   = tid >> 6, lane = tid & 63;
  const int l16  = lane & 15, g4 = lane >> 4;
  const int wr   = wv >> 2,  wc = wv & 3;

  f32x4 acc[8][4];
  #pragma unroll
  for (int i = 0; i < 8; ++i)
    #pragma unroll
    for (int j = 0; j < 4; ++j)
      acc[i][j] = (f32x4){0.f, 0.f, 0.f, 0.f};

  // stage one K-half (h) of tile tt into buffer p: 2 A-gloads + 2 B-gloads per thread.
  // wave wv covers rows [wv*32, wv*32+32). Source k permuted by the swizzle involution.
  const int swz = ((lane & 3) ^ ((lane >> 3) & 3)) << 3;  // k-elem offset in {0,8,16,24}
  const int rl  = lane >> 2;                              // 0..15
  auto SH = [&](int tt, int h, int p) {
    int kbase = tt * 64 + h * 32 + swz;
    #pragma unroll
    for (int q = 0; q < 2; ++q) {
      int r = wv * 32 + q * 16;
      gload_lds16(Ab + (size_t)(m0 + r + rl) * K + kbase, &As[p][h][r][0]);
      gload_lds16(Bb + (size_t)(n0 + r + rl) * K + kbase, &Bs[p][h][r][0]);
    }
  };

  short8v af[8], bfr[4];
  const int rslot = (g4 ^ ((l16 >> 1) & 3)) * 8;   // swizzled read slot
  auto LOADFRAGS = [&](int d, int h) {
    #pragma unroll
    for (int mf = 0; mf < 8; ++mf)
      af[mf] = *(const short8v*)&As[d][h][wr * 128 + mf * 16 + l16][rslot];
    #pragma unroll
    for (int nf = 0; nf < 4; ++nf)
      bfr[nf] = *(const short8v*)&Bs[d][h][wc * 64 + nf * 16 + l16][rslot];
  };
  auto MFMAS = [&]() {
    __builtin_amdgcn_s_setprio(1);
    #pragma unroll
    for (int mf = 0; mf < 8; ++mf)
      #pragma unroll
      for (int nf = 0; nf < 4; ++nf)
        acc[mf][nf] = __builtin_amdgcn_mfma_f32_16x16x32_bf16(af[mf], bfr[nf], acc[mf][nf], 0, 0, 0);
    __builtin_amdgcn_s_setprio(0);
  };

  const int nt = K >> 6;
  // prologue: SH0(0), SH1(0), SH0(1) -> 12 loads in flight
  SH(0, 0, 0); SH(0, 1, 0); SH(1, 0, 1);
  for (int t = 0; t < nt - 1; ++t) {
    const int d = t & 1;
    __builtin_amdgcn_sched_barrier(0);
    asm volatile("s_waitcnt vmcnt(8)" ::: "memory");   // SH0(t) landed
    __builtin_amdgcn_s_barrier();
    __builtin_amdgcn_sched_barrier(0);
    LOADFRAGS(d, 0);
    SH(t + 1, 1, d ^ 1);                               // SH1(t+1); WAR-safe (readers done pre-barrier)
    MFMAS();
    __builtin_amdgcn_sched_barrier(0);
    asm volatile("s_waitcnt vmcnt(8)" ::: "memory");   // SH1(t) landed
    __builtin_amdgcn_s_barrier();
    __builtin_amdgcn_sched_barrier(0);
    LOADFRAGS(d, 1);
    if (t + 2 < nt) SH(t + 2, 0, d);                   // SH0(t+2); overwrites k0 read in P0 (done)
    MFMAS();
    __builtin_amdgcn_sched_barrier(0);
  }
  { // peeled last tile
    const int d = (nt - 1) & 1;
    asm volatile("s_waitcnt vmcnt(4)" ::: "memory");
    __builtin_amdgcn_s_barrier();
    __builtin_amdgcn_sched_barrier(0);
    LOADFRAGS(d, 0);
    MFMAS();
    asm volatile("s_waitcnt vmcnt(0)" ::: "memory");
    __builtin_amdgcn_s_barrier();
    __builtin_amdgcn_sched_barrier(0);
    LOADFRAGS(d, 1);
    MFMAS();
  }

  const int colbase = n0 + wc * 64 + l16;
  const int rowb    = wr * 128 + g4 * 4;

  if constexpr (EPI == 2) {
    // K4: batch = zb; out/x strides 512*1024 fp32
    #pragma unroll
    for (int mf = 0; mf < 8; ++mf) {
      #pragma unroll
      for (int j = 0; j < 4; ++j) {
        int row = m0 + rowb + mf * 16 + j;
        float a  = gma[row] * rsqrtf(var[row] + EPSV);
        float bb = (bW[row] - mu[row]) * a + bta[row];
        float sc = a * (1.f / (float)NSP);
        #pragma unroll
        for (int nf = 0; nf < 4; ++nf) {
          int col = colbase + nf * 16;
          size_t idx = (size_t)zb * (CH * NSP) + (size_t)row * NSP + col;
          ((float*)Cm)[idx] = acc[mf][nf][j] * sc + bb + ((const float*)xres)[idx];
        }
      }
    }
  } else {
    // K1: batch folded into cols; b = col>>10, n = col&1023
    if (m0 < 512) {
      #pragma unroll
      for (int mf = 0; mf < 8; ++mf)
        #pragma unroll
        for (int j = 0; j < 4; ++j) {
          int row = m0 + rowb + mf * 16 + j;
          float badd = bias[row];
          #pragma unroll
          for (int nf = 0; nf < 4; ++nf) {
            int col = colbase + nf * 16;
            int b = col >> 10, n = col & 1023;
            ((bf16*)Cm)[(size_t)b * (CH * NSP) + (size_t)row * NSP + n] = f2bf(acc[mf][nf][j] + badd);
          }
        }
    } else {
      // theta tile: transposed store thT[b][n][ci], 8B packed
      #pragma unroll
      for (int mf = 0; mf < 8; ++mf) {
        int ci0 = rowb + mf * 16;   // 0..255 (m0==512)
        #pragma unroll
        for (int nf = 0; nf < 4; ++nf) {
          int col = colbase + nf * 16;
          int b = col >> 10, n = col & 1023;
          uint64_t pk = 0;
          #pragma unroll
          for (int j = 0; j < 4; ++j) {
            bf16 bv = f2bf(acc[mf][nf][j] + bias[512 + ci0 + j]);
            pk |= (uint64_t)(*(unsigned short*)&bv) << (16 * j);
          }
          *(uint64_t*)(Tt + (size_t)b * (NSP * CIc) + (size_t)n * CIc + ci0) = pk;
        }
      }
    }
  }
}

// ---------------- r3 2-phase 128x128 kernel (for small GEMMs K2/K3) ----------------
__global__ __launch_bounds__(256) void gemm_nt_small(
    const bf16* __restrict__ A, size_t sA,
    const bf16* __restrict__ Bm, size_t sB,
    bf16* __restrict__ Cm, size_t sC,
    int N, int K)
{
  __shared__ bf16 As[2][128 * 64];
  __shared__ bf16 Bs[2][128 * 64];
  const int b  = blockIdx.z;
  const int m0 = blockIdx.y * 128;
  const int n0 = blockIdx.x * 128;
  const bf16* Ab = A  + (size_t)b * sA;
  const bf16* Bb = Bm + (size_t)b * sB;
  const int tid  = threadIdx.x;
  const int wv   = tid >> 6, lane = tid & 63;
  const int l16  = lane & 15, g4 = lane >> 4;
  const int wr   = wv >> 1,  wc = wv & 1;

  f32x4 acc[4][4];
  #pragma unroll
  for (int i = 0; i < 4; ++i)
    #pragma unroll
    for (int j = 0; j < 4; ++j)
      acc[i][j] = (f32x4){0.f, 0.f, 0.f, 0.f};

  auto stage = [&](int ks, int p) {
    #pragma unroll
    for (int i = 0; i < 4; ++i) {
      int s = i * 256 + tid;
      int row = s >> 3, ch8 = (s & 7) << 3;
      gload_lds16(Ab + (size_t)(m0 + row) * K + ks + ch8, &As[p][(i * 256 + wv * 64) * 8]);
      gload_lds16(Bb + (size_t)(n0 + row) * K + ks + ch8, &Bs[p][(i * 256 + wv * 64) * 8]);
    }
  };

  const int nt = K >> 6;
  stage(0, 0);
  __syncthreads();
  for (int t = 0; t < nt; ++t) {
    const int cur = t & 1;
    if (t + 1 < nt) stage((t + 1) << 6, cur ^ 1);
    #pragma unroll
    for (int kk = 0; kk < 2; ++kk) {
      short8v af[4], bfv[4];
      #pragma unroll
      for (int mf = 0; mf < 4; ++mf)
        af[mf] = *(const short8v*)&As[cur][(wr * 64 + mf * 16 + l16) * 64 + kk * 32 + g4 * 8];
      #pragma unroll
      for (int nf = 0; nf < 4; ++nf)
        bfv[nf] = *(const short8v*)&Bs[cur][(wc * 64 + nf * 16 + l16) * 64 + kk * 32 + g4 * 8];
      #pragma unroll
      for (int mf = 0; mf < 4; ++mf)
        #pragma unroll
        for (int nf = 0; nf < 4; ++nf)
          acc[mf][nf] = __builtin_amdgcn_mfma_f32_16x16x32_bf16(af[mf], bfv[nf], acc[mf][nf], 0, 0, 0);
    }
    __syncthreads();
  }

  const int colbase = n0 + wc * 64 + l16;
  const int rowbase = m0 + wr * 64 + g4 * 4;
  #pragma unroll
  for (int mf = 0; mf < 4; ++mf)
    #pragma unroll
    for (int j = 0; j < 4; ++j) {
      int row = rowbase + mf * 16 + j;
      #pragma unroll
      for (int nf = 0; nf < 4; ++nf) {
        int col = colbase + nf * 16;
        Cm[(size_t)b * sC + (size_t)row * N + col] = f2bf(acc[mf][nf][j]);
      }
    }
}

extern "C" void kernel_launch(void* const* d_in, const int* in_sizes, int n_in,
                              void* d_out, int out_size, void* d_ws, size_t ws_size,
                              hipStream_t stream)
{
  const float* x    = (const float*)d_in[0];
  const float* w_g  = (const float*)d_in[1];
  const float* b_g  = (const float*)d_in[2];
  const float* w_th = (const float*)d_in[3];
  const float* b_th = (const float*)d_in[4];
  const float* w_ph = (const float*)d_in[5];
  const float* b_ph = (const float*)d_in[6];
  const float* w_W  = (const float*)d_in[7];
  const float* b_W  = (const float*)d_in[8];
  const float* gma  = (const float*)d_in[9];
  const float* bta  = (const float*)d_in[10];
  const float* mu   = (const float*)d_in[11];
  const float* var  = (const float*)d_in[12];
  float* out = (float*)d_out;

  char* ws = (char*)d_ws;
  bf16* proj = (bf16*)(ws + 0);            // [32][512][1024]  g(0-255), phi(256-511)
  bf16* xt   = (bf16*)(ws + 33554432);     // [32][1024][512]
  bf16* thT  = (bf16*)(ws + 67108864);     // [32][1024][256]
  bf16* S    = (bf16*)(ws + 83886080);     // [32][256][256]
  bf16* T    = (bf16*)(ws + 88080384);     // [32][512][256]
  bf16* wcat = (bf16*)(ws + 96468992);     // [768][512]
  bf16* wWb  = (bf16*)(ws + 97255424);     // [512][256]
  float* bcat= (float*)(ws + 97517568);    // [768]

  convert_weights<<<512, 256, 0, stream>>>(w_g, w_ph, w_th, b_g, b_ph, b_th, w_W, wcat, wWb, bcat);
  transpose_x_kernel<<<dim3(32, 16, 32), 256, 0, stream>>>(x, xt);

  // K1: [768 x 32768] = wcat . xt^T, K=512  (batch folded into cols)
  gemm_nt_256<1><<<dim3(128, 3, 1), 512, 0, stream>>>(
      wcat, 0, xt, 0, proj, CH, bcat, thT,
      nullptr, nullptr, nullptr, nullptr, nullptr, nullptr);

  // K2: S = phi . g^T   (M=256, N=256, K=1024) per batch
  gemm_nt_small<<<dim3(2, 2, 32), 256, 0, stream>>>(
      proj + 256 * 1024, (size_t)CH * NSP, proj, (size_t)CH * NSP, S, (size_t)CIc * CIc,
      CIc, NSP);

  // K3: T = wW . S^T    (M=512, N=256, K=256) per batch
  gemm_nt_small<<<dim3(2, 4, 32), 256, 0, stream>>>(
      wWb, 0, S, (size_t)CIc * CIc, T, (size_t)CH * CIc,
      CIc, CIc);

  // K4: out = BN(T . thT^T / N + bW) + x   (M=512, N=1024, K=256) per batch
  gemm_nt_256<2><<<dim3(4, 2, 32), 512, 0, stream>>>(
      T, (size_t)CH * CIc, thT, (size_t)NSP * CIc, out, CIc,
      nullptr, nullptr, b_W, gma, bta, mu, var, x);
}